// Round 9
// baseline (562.968 us; speedup 1.0000x reference)
//
#include <hip/hip_runtime.h>

typedef unsigned char u8;
typedef unsigned short u16;
typedef unsigned int u32;
typedef long i64;
typedef __attribute__((ext_vector_type(2))) long long2v;
typedef __attribute__((ext_vector_type(4))) float floatx4;

#define LOG2PI_F 1.8378770664093453f

// ---------- helpers ----------
__device__ __forceinline__ u16 f2bf(float f) {
  union { float f; u32 i; } c; c.f = f;
  u32 i = c.i;
  u32 r = (i + 0x7fffu + ((i >> 16) & 1u)) >> 16;   // RNE (inputs finite)
  return (u16)r;
}
__device__ __forceinline__ float bf2f(u16 u) {
  union { u32 i; float f; } c; c.i = ((u32)u) << 16; return c.f;
}
__device__ __forceinline__ u8 f2fp8(float f) {
  int p = __builtin_amdgcn_cvt_pk_fp8_f32(f, f, 0, false);
  return (u8)(p & 0xff);
}
__device__ __forceinline__ u32 pk4fp8(float a, float b, float c, float d) {
  int lo = __builtin_amdgcn_cvt_pk_fp8_f32(a, b, 0, false);
  int v  = __builtin_amdgcn_cvt_pk_fp8_f32(c, d, lo, true);
  return (u32)v;
}
// fast tanh: (t-1)/(t+1), t=exp(2x). 1-ulp-ish, swamped by fp8 quantization.
// clamp avoids inf*0=NaN; tanh(10)=1-4e-9 == 1.0f in fp8.
__device__ __forceinline__ float fast_tanh(float x) {
  float xc = fminf(fmaxf(x, -10.f), 10.f);
  float t = __expf(2.f * xc);
  return (t - 1.f) * __builtin_amdgcn_rcpf(t + 1.f);
}
__device__ __forceinline__ void llds16(const void* g, void* l) {
  __builtin_amdgcn_global_load_lds(
      (const __attribute__((address_space(1))) u32*)g,
      (__attribute__((address_space(3))) u32*)l, 16, 0, 0);
}
// K-storage permutation: per 64-k group, octet order O0,O4,O1,O5,O2,O6,O3,O7
// so (h0,h1) octet pairs for quad q are the two 8B halves of 16B chunk q.
__device__ __forceinline__ u32 permk(u32 k) {
  u32 g = k & ~63u, o = (k >> 3) & 7u, r = k & 7u;
  u32 po = ((o & 3u) << 1) | (o >> 2);
  return g | (po << 3) | r;
}

// Scales (powers of 2; keep e4m3 out of subnormals):
//   x*16, weights*256, tanh-activations*64, z*16. Inverses folded into epilogues.
#define INV_4096  2.44140625e-4f
#define INV_16384 6.103515625e-5f

// ---------- packing kernels ----------
__global__ void pack_xb(const float* __restrict__ in, u32* __restrict__ out, int n4) {
  int i = blockIdx.x * 256 + threadIdx.x;
  if (i >= n4) return;
  const float4 v = ((const float4*)in)[i];
  int row = i >> 7;                    // D/4 = 128
  int k = (i & 127) << 2;
  int kp = permk(k);                   // float4 stays inside one octet
  out[(row << 7) + (kp >> 2)] = pk4fp8(v.x * 16.f, v.y * 16.f, v.z * 16.f, v.w * 16.f);
}

// W [K][N] fp32 -> Wt [N][permk(K)] fp8 (*256)
__global__ void pack_wt(const float* __restrict__ W, u8* __restrict__ Wt, int K, int N) {
  int idx = blockIdx.x * 256 + threadIdx.x;
  if (idx >= K * N) return;
  int k = idx / N, n = idx - k * N;
  Wt[(size_t)n * K + permk(k)] = f2fp8(W[idx] * 256.f);
}

// W1 [K][N1], W2 [K][N2] fp32 -> Wt [(N1+N2)][permk(K)] fp8 (*256)
__global__ void pack_wt2(const float* __restrict__ W1, const float* __restrict__ W2,
                         u8* __restrict__ Wt, int K, int N1, int N2) {
  int idx = blockIdx.x * 256 + threadIdx.x;
  if (idx >= (N1 + N2) * K) return;
  int n = idx / K, k = idx - n * K;
  float v = (n < N1) ? W1[(size_t)k * N1 + n] : W2[(size_t)k * N2 + (n - N1)];
  Wt[(size_t)n * K + permk(k)] = f2fp8(v * 256.f);
}

__global__ void catf(const float* __restrict__ a, const float* __restrict__ b,
                     float* __restrict__ o, int n1, int n2) {
  int i = blockIdx.x * 256 + threadIdx.x;
  if (i < n1) o[i] = a[i];
  else if (i < n1 + n2) o[i] = b[i - n1];
}

// ---------- fp8 MFMA GEMM, 128x128 tile (GEMM4 only: K=64, single K-tile) ----------
// A: [M][K] fp8 (K permuted), Bt: [N][K] fp8 (K permuted), bias: [N] f32.
// Epilogue: fast_tanh -> fp8*outs, staged through LDS (permk applied there), then
// fully-linear dwordx4 global stores (no write amplification).
__global__ __launch_bounds__(256) void gemm_bt0(
    const u8* __restrict__ A, const u8* __restrict__ Bt,
    const float* __restrict__ bias, u8* __restrict__ C,
    float inv, float outs, int M, int N, int K) {
  __shared__ __align__(16) u8 smem[16384];
  u8* As = smem;
  u8* Bs = smem + 8192;
  const int t = threadIdx.x;
  const int wave = t >> 6, lane = t & 63;
  const int quad = lane >> 4, l16 = lane & 15;
  const int bm = blockIdx.y * 128, bn = blockIdx.x * 128;
  const int wm = (wave >> 1) * 64, wn = (wave & 1) * 64;

  floatx4 acc[4][4];
#pragma unroll
  for (int i = 0; i < 4; ++i)
#pragma unroll
    for (int j = 0; j < 4; ++j) acc[i][j] = (floatx4){0.f, 0.f, 0.f, 0.f};

  for (int kt = 0; kt < K; kt += 64) {
#pragma unroll
    for (int i = 0; i < 2; ++i) {
      int c = i * 256 + t;
      int r = c >> 2, kcS = c & 3;
      int kc = kcS ^ ((r >> 1) & 3);
      llds16(A + (size_t)(bm + r) * K + kt + kc * 16, &As[c * 16]);
      llds16(Bt + (size_t)(bn + r) * K + kt + kc * 16, &Bs[c * 16]);
    }
    __builtin_amdgcn_s_waitcnt(0);
    __syncthreads();

    long2v a2[4], b2[4];
#pragma unroll
    for (int mi = 0; mi < 4; ++mi) {
      int m = wm + mi * 16 + l16;
      a2[mi] = *(const long2v*)&As[(4 * m + (quad ^ ((m >> 1) & 3))) * 16];
    }
#pragma unroll
    for (int ni = 0; ni < 4; ++ni) {
      int n = wn + ni * 16 + l16;
      b2[ni] = *(const long2v*)&Bs[(4 * n + (quad ^ ((n >> 1) & 3))) * 16];
    }
#pragma unroll
    for (int h = 0; h < 2; ++h)
#pragma unroll
      for (int mi = 0; mi < 4; ++mi)
#pragma unroll
        for (int ni = 0; ni < 4; ++ni)
          acc[mi][ni] = __builtin_amdgcn_mfma_f32_16x16x32_fp8_fp8(
              a2[mi][h], b2[ni][h], acc[mi][ni], 0, 0, 0);
    __syncthreads();
  }

  // ---- epilogue: stage 128x128 fp8 tile in LDS (permk cols), linear stores ----
#pragma unroll
  for (int ni = 0; ni < 4; ++ni) {
    int col = wn + ni * 16 + l16;
    float bv = bias[bn + col];
    u32 pc = permk((u32)col);
#pragma unroll
    for (int mi = 0; mi < 4; ++mi) {
#pragma unroll
      for (int r = 0; r < 4; ++r) {
        int row = wm + mi * 16 + quad * 4 + r;
        float v = acc[mi][ni][r] * inv + bv;
        smem[row * 128 + pc] = f2fp8(fast_tanh(v) * outs);
      }
    }
  }
  __syncthreads();
#pragma unroll
  for (int j = 0; j < 4; ++j) {
    int u = j * 256 + t;                 // 1024 x 16B units
    int row = u >> 3, c16 = u & 7;
    *(long2v*)(C + (size_t)(bm + row) * N + bn + c16 * 16) =
        *(const long2v*)&smem[row * 128 + c16 * 16];
  }
}

// ---------- fp8 MFMA GEMM (256x256 tile, register read-ahead) ----------
// 512 threads = 8 waves (2M x 4N), per-wave 128x64 output. BK=64.
// DEPTH=4 LDS ring (128 KB), stage LEAD=2, counted vmcnt(4) (never 0 mid-loop).
// TWO HW-VERIFIED BODIES selected by FINE:
//  FINE=0 (round-3): coarse 64-MFMA cluster per tile. Best for GEMM1 (nt=8,
//          light K; extra barriers of the fine body cost ~10us there, round 8).
//  FINE=1 (round-8): 4 sub-phases of 16 MFMA, s_barrier-coupled alternating
//          all-MFMA/all-memory bursts; B(ti+1) reads one per sub-phase;
//          sched_barrier(0) pins bursts (rule #18). GEMM5 123.6->115.8us,
//          MfmaUtil 46.5->49.5%, VGPR 128, no spill.
// ROUND-4/6 LESSON: do NOT widen (16-wave and pair-phase both spill acc).
// Race-freedom (both bodies): tile-body reads touch slots ti/ti+1 only; async
// stage writes slot (ti+2)&3; intra-tile barriers unconditional and uniform.
// Epilogue staged through LDS -> linear dwordx4 stores.
template <int EPI, int FINE>
__global__ __launch_bounds__(512, 2) void gemm256(
    const u8* __restrict__ A, const u8* __restrict__ Bt,
    const float* __restrict__ bias, void* __restrict__ Cv,
    float inv, float outs, int M, int N, int K) {
  __shared__ __align__(16) u8 lds[4][2][256 * 64];   // ring: 128 KB; reused by epilogue
  const int t = threadIdx.x;
  const int wave = t >> 6, lane = t & 63;
  const int quad = lane >> 4, l16 = lane & 15;
  // XCD-aware swizzle (bijective: nwg % 8 == 0 for all our launches; guarded)
  const int nbx = N >> 8;
  const int nwg = nbx * (M >> 8);
  int raw = blockIdx.x + nbx * blockIdx.y;
  int wgid = ((nwg & 7) == 0) ? ((raw & 7) * (nwg >> 3) + (raw >> 3)) : raw;
  const int bm = (wgid / nbx) << 8, bn = (wgid % nbx) << 8;
  const int wm = (wave >> 2) * 128, wn = (wave & 3) * 64;
  const int nt = K >> 6;

  // stage K-tile ti into ring slot ti&3: 4 llds16/thread (vmcnt +4 per stage)
  auto stage = [&](int ti) {
    const int b = ti & 3;
    const int kt = ti << 6;
#pragma unroll
    for (int i = 0; i < 2; ++i) {
      int c = i * 512 + t;               // 0..1023 chunks of 16B
      int r = c >> 2, kcS = c & 3;
      int kc = kcS ^ ((r >> 1) & 3);
      llds16(A + (size_t)(bm + r) * K + kt + kc * 16, &lds[b][0][c * 16]);
    }
#pragma unroll
    for (int i = 0; i < 2; ++i) {
      int c = i * 512 + t;
      int r = c >> 2, kcS = c & 3;
      int kc = kcS ^ ((r >> 1) & 3);
      llds16(Bt + (size_t)(bn + r) * K + kt + kc * 16, &lds[b][1][c * 16]);
    }
  };

  // precomputed per-lane fragment byte offsets within a slot half
  int offA[8], offB[4];
#pragma unroll
  for (int mi = 0; mi < 8; ++mi) {
    int m = wm + mi * 16 + l16;
    offA[mi] = (4 * m + (quad ^ ((m >> 1) & 3))) * 16;
  }
#pragma unroll
  for (int ni = 0; ni < 4; ++ni) {
    int n = wn + ni * 16 + l16;
    offB[ni] = (4 * n + (quad ^ ((n >> 1) & 3))) * 16;
  }

  floatx4 acc[8][4];
#pragma unroll
  for (int i = 0; i < 8; ++i)
#pragma unroll
    for (int j = 0; j < 4; ++j) acc[i][j] = (floatx4){0.f, 0.f, 0.f, 0.f};

  long2v a2[8], b2[4], b3[4];

  // prologue: stage tiles 0,1; wait tile 0; load tile-0 fragments
  stage(0);
  stage(1);
  asm volatile("s_waitcnt vmcnt(4)" ::: "memory");
  __builtin_amdgcn_s_barrier();
  asm volatile("" ::: "memory");
  {
    const u8* bA = &lds[0][0][0];
    const u8* bB = &lds[0][1][0];
#pragma unroll
    for (int ni = 0; ni < 4; ++ni) b2[ni] = *(const long2v*)(bB + offB[ni]);
#pragma unroll
    for (int mi = 0; mi < 8; ++mi) a2[mi] = *(const long2v*)(bA + offA[mi]);
  }

// common phase prologue: stage lead tile, counted vmcnt, barrier, slot ptrs
#define GHEAD(TI)                                                             \
    const int ti_ = (TI);                                                     \
    if (ti_ + 2 < nt) {                                                       \
      stage(ti_ + 2);                                                         \
      asm volatile("s_waitcnt vmcnt(4)" ::: "memory");                        \
    } else {                                                                  \
      asm volatile("s_waitcnt vmcnt(0)" ::: "memory");                        \
    }                                                                         \
    __builtin_amdgcn_s_barrier();                                             \
    asm volatile("" ::: "memory");                                            \
    const u8* bA_ = &lds[(ti_ + 1) & 3][0][0];                                \
    const u8* bB_ = &lds[(ti_ + 1) & 3][1][0];

// round-3 coarse body: one 64-MFMA cluster, WAR A-reload after last use
#define GBODY_C(TI, BCUR, BNXT) {                                             \
    GHEAD(TI)                                                                 \
    _Pragma("unroll")                                                         \
    for (int ni = 0; ni < 4; ++ni) BNXT[ni] = *(const long2v*)(bB_ + offB[ni]);\
    __builtin_amdgcn_s_setprio(1);                                            \
    _Pragma("unroll")                                                         \
    for (int mi = 0; mi < 8; ++mi) {                                          \
      _Pragma("unroll")                                                       \
      for (int h = 0; h < 2; ++h)                                             \
        _Pragma("unroll")                                                     \
        for (int ni = 0; ni < 4; ++ni)                                        \
          acc[mi][ni] = __builtin_amdgcn_mfma_f32_16x16x32_fp8_fp8(           \
              a2[mi][h], BCUR[ni][h], acc[mi][ni], 0, 0, 0);                  \
      a2[mi] = *(const long2v*)(bA_ + offA[mi]);                              \
    }                                                                         \
    __builtin_amdgcn_s_setprio(0);                                            \
  }

// round-8 fine body: 4 sub-phases of 16 MFMA, barrier-coupled bursts
#define GBODY_F(TI, BCUR, BNXT) {                                             \
    GHEAD(TI)                                                                 \
    _Pragma("unroll")                                                         \
    for (int q = 0; q < 4; ++q) {                                             \
      BNXT[q] = *(const long2v*)(bB_ + offB[q]);                              \
      __builtin_amdgcn_sched_barrier(0);                                      \
      __builtin_amdgcn_s_setprio(1);                                          \
      _Pragma("unroll")                                                       \
      for (int mq = 0; mq < 2; ++mq) {                                        \
        _Pragma("unroll")                                                     \
        for (int h = 0; h < 2; ++h)                                           \
          _Pragma("unroll")                                                   \
          for (int ni = 0; ni < 4; ++ni)                                      \
            acc[2 * q + mq][ni] = __builtin_amdgcn_mfma_f32_16x16x32_fp8_fp8( \
                a2[2 * q + mq][h], BCUR[ni][h], acc[2 * q + mq][ni], 0, 0, 0);\
      }                                                                       \
      __builtin_amdgcn_s_setprio(0);                                          \
      __builtin_amdgcn_sched_barrier(0);                                      \
      a2[2 * q]     = *(const long2v*)(bA_ + offA[2 * q]);                    \
      a2[2 * q + 1] = *(const long2v*)(bA_ + offA[2 * q + 1]);                \
      if (q < 3) { __builtin_amdgcn_s_barrier(); }                            \
    }                                                                         \
  }

  int ti = 0;
  for (; ti + 2 < nt; ti += 2) {        // nt is even (8 or 16)
    if constexpr (FINE) { GBODY_F(ti, b2, b3); GBODY_F(ti + 1, b3, b2); }
    else                { GBODY_C(ti, b2, b3); GBODY_C(ti + 1, b3, b2); }
  }
  if constexpr (FINE) { GBODY_F(ti, b2, b3); }   // ti == nt-2
  else                { GBODY_C(ti, b2, b3); }
#undef GBODY_C
#undef GBODY_F
#undef GHEAD
  // peeled last K-tile: pure MFMA on a2 / b3
  __builtin_amdgcn_s_setprio(1);
#pragma unroll
  for (int mi = 0; mi < 8; ++mi)
#pragma unroll
    for (int h = 0; h < 2; ++h)
#pragma unroll
      for (int ni = 0; ni < 4; ++ni)
        acc[mi][ni] = __builtin_amdgcn_mfma_f32_16x16x32_fp8_fp8(
            a2[mi][h], b3[ni][h], acc[mi][ni], 0, 0, 0);
  __builtin_amdgcn_s_setprio(0);

  // ---- epilogue: stage full 256x256 tile in LDS, then linear stores ----
  __syncthreads();                       // all ring ds_reads retired block-wide
  u8* eb = &lds[0][0][0];                // 128 KB staging
  if (EPI == 0) {
    // fp8 out, permk cols applied at LDS write; 64 KB used
#pragma unroll
    for (int ni = 0; ni < 4; ++ni) {
      int col = wn + ni * 16 + l16;
      float bv = bias[bn + col];
      u32 pc = permk((u32)col);
#pragma unroll
      for (int mi = 0; mi < 8; ++mi) {
#pragma unroll
        for (int r = 0; r < 4; ++r) {
          int row = wm + mi * 16 + quad * 4 + r;
          float v = acc[mi][ni][r] * inv + bv;
          eb[row * 256 + pc] = f2fp8(fast_tanh(v) * outs);
        }
      }
    }
    __syncthreads();
#pragma unroll
    for (int j = 0; j < 8; ++j) {
      int u = j * 512 + t;               // 4096 x 16B units
      int row = u >> 4, c16 = u & 15;
      *(long2v*)((u8*)Cv + (size_t)(bm + row) * N + bn + c16 * 16) =
          *(const long2v*)&eb[row * 256 + c16 * 16];
    }
  } else {
    // bf16 out, natural cols; 128 KB used
    u16* ebw = (u16*)eb;
#pragma unroll
    for (int ni = 0; ni < 4; ++ni) {
      int col = wn + ni * 16 + l16;
      float bv = bias[bn + col];
#pragma unroll
      for (int mi = 0; mi < 8; ++mi) {
#pragma unroll
        for (int r = 0; r < 4; ++r) {
          int row = wm + mi * 16 + quad * 4 + r;
          float v = acc[mi][ni][r] * inv + bv;
          ebw[row * 256 + col] = f2bf(v);
        }
      }
    }
    __syncthreads();
#pragma unroll
    for (int j = 0; j < 16; ++j) {
      int u = j * 512 + t;               // 8192 x 16B units
      int row = u >> 5, c16 = u & 31;
      *(long2v*)((u16*)Cv + (size_t)(bm + row) * N + bn + c16 * 8) =
          *(const long2v*)&ebw[row * 256 + c16 * 8];
    }
  }
}

// ---------- fused GEMM23 + reparameterise + KL (fp8) ----------
// A: [M][K] fp8 (h*64, K permuted), Bt: [128][K] fp8, bias [128].
// Cols 0..63 = mu_z, 64..127 = lv_z. Writes z [M][permk(64)] fp8 (*16).
__global__ __launch_bounds__(256) void gemm_z(
    const u8* __restrict__ A, const u8* __restrict__ Bt,
    const float* __restrict__ bias, const float* __restrict__ eps,
    u8* __restrict__ z, float* __restrict__ accp, int M, int K) {
  __shared__ __align__(16) u8 As[128 * 64];
  __shared__ __align__(16) u8 Bs[128 * 64];
  __shared__ float sexp[128 * 64];   // exp(0.5*lv) staging [row][col]
  const int t = threadIdx.x;
  const int wave = t >> 6, lane = t & 63;
  const int quad = lane >> 4, l16 = lane & 15;
  const int bm = blockIdx.y * 128;
  const int wm = (wave >> 1) * 64, wn = (wave & 1) * 64;

  floatx4 acc[4][4];
#pragma unroll
  for (int i = 0; i < 4; ++i)
#pragma unroll
    for (int j = 0; j < 4; ++j) acc[i][j] = (floatx4){0.f, 0.f, 0.f, 0.f};

  for (int kt = 0; kt < K; kt += 64) {
#pragma unroll
    for (int i = 0; i < 2; ++i) {
      int c = i * 256 + t;
      int r = c >> 2, kcS = c & 3;
      int kc = kcS ^ ((r >> 1) & 3);
      llds16(A + (size_t)(bm + r) * K + kt + kc * 16, &As[c * 16]);
      llds16(Bt + (size_t)r * K + kt + kc * 16, &Bs[c * 16]);
    }
    __builtin_amdgcn_s_waitcnt(0);
    __syncthreads();

    long2v a2[4], b2[4];
#pragma unroll
    for (int mi = 0; mi < 4; ++mi) {
      int m = wm + mi * 16 + l16;
      a2[mi] = *(const long2v*)&As[(4 * m + (quad ^ ((m >> 1) & 3))) * 16];
    }
#pragma unroll
    for (int ni = 0; ni < 4; ++ni) {
      int n = wn + ni * 16 + l16;
      b2[ni] = *(const long2v*)&Bs[(4 * n + (quad ^ ((n >> 1) & 3))) * 16];
    }
#pragma unroll
    for (int h = 0; h < 2; ++h)
#pragma unroll
      for (int mi = 0; mi < 4; ++mi)
#pragma unroll
        for (int ni = 0; ni < 4; ++ni)
          acc[mi][ni] = __builtin_amdgcn_mfma_f32_16x16x32_fp8_fp8(
              a2[mi][h], b2[ni][h], acc[mi][ni], 0, 0, 0);
    __syncthreads();
  }

  const bool is_lv = (wave & 1);
  float kl = 0.f;
#pragma unroll
  for (int ni = 0; ni < 4; ++ni) {
    int col = wn + ni * 16 + l16;            // 0..127
    float bv = bias[col];
#pragma unroll
    for (int mi = 0; mi < 4; ++mi) {
#pragma unroll
      for (int r = 0; r < 4; ++r) {
        int row = wm + mi * 16 + quad * 4 + r;   // 0..127 local
        float v = acc[mi][ni][r] * INV_16384 + bv;
        if (is_lv) {
          kl += 1.0f + v - __expf(v);
          sexp[row * 64 + (col - 64)] = __expf(0.5f * v);
        } else {
          kl -= v * v;
        }
      }
    }
  }
  __syncthreads();
  if (!is_lv) {
#pragma unroll
    for (int ni = 0; ni < 4; ++ni) {
      int col = wn + ni * 16 + l16;          // 0..63
      float bv = bias[col];
#pragma unroll
      for (int mi = 0; mi < 4; ++mi) {
#pragma unroll
        for (int r = 0; r < 4; ++r) {
          int row = wm + mi * 16 + quad * 4 + r;
          float mu = acc[mi][ni][r] * INV_16384 + bv;
          size_t grow = (size_t)(bm + row);
          float ep = eps[grow * 64 + col];
          z[grow * 64 + permk(col)] = f2fp8((mu + sexp[row * 64 + col] * ep) * 16.f);
        }
      }
    }
  }
  kl *= 0.5f;
  for (int off = 32; off > 0; off >>= 1) kl += __shfl_xor(kl, off, 64);
  __shared__ float s4[4];
  if (lane == 0) s4[wave] = kl;
  __syncthreads();
  if (t == 0) atomicAdd(accp, s4[0] + s4[1] + s4[2] + s4[3]);
}

// ---------- softmax + diag-Gaussian log-likelihood ----------
// loglv: [B][1024] bf16 (0..511 logits, 512..1023 lv_x); x: [B][512] f32
__global__ __launch_bounds__(256) void lik_kernel(
    const u16* __restrict__ loglv, const float* __restrict__ x,
    float* __restrict__ acc) {
  typedef __attribute__((ext_vector_type(8))) short short8;
  const int wave = threadIdx.x >> 6, lane = threadIdx.x & 63;
  float wacc = 0.f;
  for (int rr = 0; rr < 8; ++rr) {
    int row = blockIdx.x * 32 + wave * 8 + rr;
    const u16* Lr = loglv + (size_t)row * 1024;
    short8 lg8 = ((const short8*)Lr)[lane];
    float lg[8];
#pragma unroll
    for (int j = 0; j < 8; ++j) lg[j] = bf2f((u16)lg8[j]);
    float mx = lg[0];
#pragma unroll
    for (int j = 1; j < 8; ++j) mx = fmaxf(mx, lg[j]);
    for (int off = 32; off > 0; off >>= 1) mx = fmaxf(mx, __shfl_xor(mx, off, 64));
    float e[8], s = 0.f;
#pragma unroll
    for (int j = 0; j < 8; ++j) { e[j] = __expf(lg[j] - mx); s += e[j]; }
    for (int off = 32; off > 0; off >>= 1) s += __shfl_xor(s, off, 64);
    float inv_s = 1.0f / s;
    short8 lv8 = ((const short8*)Lr)[64 + lane];
    const float* xr = x + (size_t)row * 512 + lane * 8;
    float4 x0 = *(const float4*)xr, x1 = *(const float4*)(xr + 4);
    float xs[8] = {x0.x, x0.y, x0.z, x0.w, x1.x, x1.y, x1.z, x1.w};
    float T = 0.f;
#pragma unroll
    for (int j = 0; j < 8; ++j) {
      float lv = bf2f((u16)lv8[j]);
      float d = xs[j] - e[j] * inv_s;
      T += lv + d * d * __expf(-lv) + LOG2PI_F;
    }
    for (int off = 32; off > 0; off >>= 1) T += __shfl_xor(T, off, 64);
    if (lane == 0) wacc += -0.5f * T;
  }
  __shared__ float s4[4];
  if (lane == 0) s4[wave] = wacc;
  __syncthreads();
  if (threadIdx.x == 0) atomicAdd(acc, s4[0] + s4[1] + s4[2] + s4[3]);
}

__global__ void fin_kernel(const float* __restrict__ acc, float* __restrict__ out) {
  out[0] = acc[0] * (1.0f / 65536.0f);
}

// ---------- launch ----------
extern "C" void kernel_launch(void* const* d_in, const int* in_sizes, int n_in,
                              void* d_out, int out_size, void* d_ws, size_t ws_size,
                              hipStream_t stream) {
  const int B = 65536, D = 512, H = 1024, L = 64;
  const float* x       = (const float*)d_in[0];
  const float* eps     = (const float*)d_in[1];
  const float* W_enc_h = (const float*)d_in[2];
  const float* b_enc_h = (const float*)d_in[3];
  const float* W_enc_mu= (const float*)d_in[4];
  const float* b_enc_mu= (const float*)d_in[5];
  const float* W_enc_lv= (const float*)d_in[6];
  const float* b_enc_lv= (const float*)d_in[7];
  const float* W_dec_h = (const float*)d_in[8];
  const float* b_dec_h = (const float*)d_in[9];
  const float* W_dec_mu= (const float*)d_in[10];
  const float* b_dec_mu= (const float*)d_in[11];
  const float* W_dec_lv= (const float*)d_in[12];
  const float* b_dec_lv= (const float*)d_in[13];

  char* ws = (char*)d_ws;
  // weights (fp8) / bias / acc block
  u8*   Wt_eh  = (u8*)(ws + 0);             // [1024][512]  512K
  u8*   Wt_z   = (u8*)(ws + 524288);        // [128][1024]  128K
  u8*   Wt_dh  = (u8*)(ws + 655360);        // [1024][64]    64K
  u8*   Wt_dx  = (u8*)(ws + 720896);        // [1024][1024]   1M
  float* bh    = (float*)(ws + 2097152);    // [1024]
  float* bz    = (float*)(ws + 2101248);    // [128]
  float* bdh   = (float*)(ws + 2105344);    // [1024]
  float* bdx   = (float*)(ws + 2109440);    // [1024]
  float* acc   = (float*)(ws + 2113536);    // [1]
  // big regions (peak 232 MB)
  u8*   hbuf   = (u8*)(ws + 4194304);       // [B][1024] fp8: h then hd (64MB)
  u8*   xb     = (u8*)(ws + 71303168);      // [B][512] fp8 (32MB, dead after GEMM1)
  u8*   zbuf   = (u8*)(ws + 104857600);     // [B][64] fp8 (4MB, dead after GEMM4)
  u16*  loglv  = (u16*)(ws + 109051904);    // [B][1024] bf16 (128MB)

  hipMemsetAsync(acc, 0, 256, stream);

  // ---- packing ----
  pack_xb<<<(B * D / 4 + 255) / 256, 256, 0, stream>>>(x, (u32*)xb, B * D / 4);
  pack_wt<<<(D * H + 255) / 256, 256, 0, stream>>>(W_enc_h, Wt_eh, D, H);
  pack_wt2<<<(H * 2 * L + 255) / 256, 256, 0, stream>>>(W_enc_mu, W_enc_lv, Wt_z, H, L, L);
  pack_wt<<<(L * H + 255) / 256, 256, 0, stream>>>(W_dec_h, Wt_dh, L, H);
  pack_wt2<<<(H * 2 * D + 255) / 256, 256, 0, stream>>>(W_dec_mu, W_dec_lv, Wt_dx, H, D, D);
  catf<<<(H + 255) / 256, 256, 0, stream>>>(b_enc_h, b_enc_h, bh, H, 0);
  catf<<<(2 * L + 255) / 256, 256, 0, stream>>>(b_enc_mu, b_enc_lv, bz, L, L);
  catf<<<(H + 255) / 256, 256, 0, stream>>>(b_dec_h, b_dec_h, bdh, H, 0);
  catf<<<(2 * D + 255) / 256, 256, 0, stream>>>(b_dec_mu, b_dec_lv, bdx, D, D);

  // ---- encoder: h = tanh(x @ W_enc_h + b), fp8*64, K-permuted (coarse body) ----
  gemm256<0, 0><<<dim3(H / 256, B / 256), 512, 0, stream>>>(
      xb, Wt_eh, bh, hbuf, INV_4096, 64.f, B, H, D);
  // ---- fused: mu|lv = h @ Wt_z + b ; z = mu + exp(.5 lv) eps (fp8*16) ; KL ----
  gemm_z<<<dim3(1, B / 128), 256, 0, stream>>>(hbuf, Wt_z, bz, eps, zbuf, acc, B, H);
  // ---- decoder hidden: hd = tanh(z @ W_dec_h + b), fp8*64 (K=64: 128^2 kernel) ----
  gemm_bt0<<<dim3(H / 128, B / 128), 256, 0, stream>>>(
      zbuf, Wt_dh, bdh, hbuf, INV_4096, 64.f, B, H, L);
  // ---- logits | lv_x = hd @ [W_dec_mu|W_dec_lv] + b -> bf16 (fine body) ----
  gemm256<2, 1><<<dim3(1024 / 256, B / 256), 512, 0, stream>>>(
      hbuf, Wt_dx, bdx, loglv, INV_16384, 0.f, B, 1024, H);
  // ---- softmax + log-likelihood ----
  lik_kernel<<<B / 32, 256, 0, stream>>>(loglv, x, acc);
  // ---- finalize mean ----
  fin_kernel<<<1, 1, 0, stream>>>(acc, (float*)d_out);
}

// Round 10
// 551.186 us; speedup vs baseline: 1.0214x; 1.0214x over previous
//
#include <hip/hip_runtime.h>

typedef unsigned char u8;
typedef unsigned short u16;
typedef unsigned int u32;
typedef long i64;
typedef __attribute__((ext_vector_type(2))) long long2v;
typedef __attribute__((ext_vector_type(4))) float floatx4;

#define LOG2PI_F 1.8378770664093453f

// ---------- helpers ----------
__device__ __forceinline__ u16 f2bf(float f) {
  union { float f; u32 i; } c; c.f = f;
  u32 i = c.i;
  u32 r = (i + 0x7fffu + ((i >> 16) & 1u)) >> 16;   // RNE (inputs finite)
  return (u16)r;
}
__device__ __forceinline__ float bf2f(u16 u) {
  union { u32 i; float f; } c; c.i = ((u32)u) << 16; return c.f;
}
__device__ __forceinline__ u8 f2fp8(float f) {
  int p = __builtin_amdgcn_cvt_pk_fp8_f32(f, f, 0, false);
  return (u8)(p & 0xff);
}
__device__ __forceinline__ u32 pk4fp8(float a, float b, float c, float d) {
  int lo = __builtin_amdgcn_cvt_pk_fp8_f32(a, b, 0, false);
  int v  = __builtin_amdgcn_cvt_pk_fp8_f32(c, d, lo, true);
  return (u32)v;
}
// fast tanh: (t-1)/(t+1), t=exp(2x). 1-ulp-ish, swamped by fp8 quantization.
// clamp avoids inf*0=NaN; tanh(10)=1-4e-9 == 1.0f in fp8.
__device__ __forceinline__ float fast_tanh(float x) {
  float xc = fminf(fmaxf(x, -10.f), 10.f);
  float t = __expf(2.f * xc);
  return (t - 1.f) * __builtin_amdgcn_rcpf(t + 1.f);
}
__device__ __forceinline__ void llds16(const void* g, void* l) {
  __builtin_amdgcn_global_load_lds(
      (const __attribute__((address_space(1))) u32*)g,
      (__attribute__((address_space(3))) u32*)l, 16, 0, 0);
}
// K-storage permutation: per 64-k group, octet order O0,O4,O1,O5,O2,O6,O3,O7
// so (h0,h1) octet pairs for quad q are the two 8B halves of 16B chunk q.
__device__ __forceinline__ u32 permk(u32 k) {
  u32 g = k & ~63u, o = (k >> 3) & 7u, r = k & 7u;
  u32 po = ((o & 3u) << 1) | (o >> 2);
  return g | (po << 3) | r;
}

// Scales (powers of 2; keep e4m3 out of subnormals):
//   x*16, weights*256, tanh-activations*64, z*16. Inverses folded into epilogues.
#define INV_4096  2.44140625e-4f
#define INV_16384 6.103515625e-5f

// ---------- packing kernels ----------
__global__ void pack_xb(const float* __restrict__ in, u32* __restrict__ out, int n4) {
  int i = blockIdx.x * 256 + threadIdx.x;
  if (i >= n4) return;
  const float4 v = ((const float4*)in)[i];
  int row = i >> 7;                    // D/4 = 128
  int k = (i & 127) << 2;
  int kp = permk(k);                   // float4 stays inside one octet
  out[(row << 7) + (kp >> 2)] = pk4fp8(v.x * 16.f, v.y * 16.f, v.z * 16.f, v.w * 16.f);
}

// W [K][N] fp32 -> Wt [N][permk(K)] fp8 (*256)
__global__ void pack_wt(const float* __restrict__ W, u8* __restrict__ Wt, int K, int N) {
  int idx = blockIdx.x * 256 + threadIdx.x;
  if (idx >= K * N) return;
  int k = idx / N, n = idx - k * N;
  Wt[(size_t)n * K + permk(k)] = f2fp8(W[idx] * 256.f);
}

// W1 [K][N1], W2 [K][N2] fp32 -> Wt [(N1+N2)][permk(K)] fp8 (*256)
__global__ void pack_wt2(const float* __restrict__ W1, const float* __restrict__ W2,
                         u8* __restrict__ Wt, int K, int N1, int N2) {
  int idx = blockIdx.x * 256 + threadIdx.x;
  if (idx >= (N1 + N2) * K) return;
  int n = idx / K, k = idx - n * K;
  float v = (n < N1) ? W1[(size_t)k * N1 + n] : W2[(size_t)k * N2 + (n - N1)];
  Wt[(size_t)n * K + permk(k)] = f2fp8(v * 256.f);
}

__global__ void catf(const float* __restrict__ a, const float* __restrict__ b,
                     float* __restrict__ o, int n1, int n2) {
  int i = blockIdx.x * 256 + threadIdx.x;
  if (i < n1) o[i] = a[i];
  else if (i < n1 + n2) o[i] = b[i - n1];
}

// ---------- fp8 MFMA GEMM, 128x128 tile (GEMM4 only: K=64, single K-tile) ----------
// A: [M][K] fp8 (K permuted), Bt: [N][K] fp8 (K permuted), bias: [N] f32.
// Epilogue: fast_tanh -> fp8*outs, staged through LDS (permk applied there), then
// fully-linear dwordx4 global stores (no write amplification).
__global__ __launch_bounds__(256) void gemm_bt0(
    const u8* __restrict__ A, const u8* __restrict__ Bt,
    const float* __restrict__ bias, u8* __restrict__ C,
    float inv, float outs, int M, int N, int K) {
  __shared__ __align__(16) u8 smem[16384];
  u8* As = smem;
  u8* Bs = smem + 8192;
  const int t = threadIdx.x;
  const int wave = t >> 6, lane = t & 63;
  const int quad = lane >> 4, l16 = lane & 15;
  const int bm = blockIdx.y * 128, bn = blockIdx.x * 128;
  const int wm = (wave >> 1) * 64, wn = (wave & 1) * 64;

  floatx4 acc[4][4];
#pragma unroll
  for (int i = 0; i < 4; ++i)
#pragma unroll
    for (int j = 0; j < 4; ++j) acc[i][j] = (floatx4){0.f, 0.f, 0.f, 0.f};

  for (int kt = 0; kt < K; kt += 64) {
#pragma unroll
    for (int i = 0; i < 2; ++i) {
      int c = i * 256 + t;
      int r = c >> 2, kcS = c & 3;
      int kc = kcS ^ ((r >> 1) & 3);
      llds16(A + (size_t)(bm + r) * K + kt + kc * 16, &As[c * 16]);
      llds16(Bt + (size_t)(bn + r) * K + kt + kc * 16, &Bs[c * 16]);
    }
    __builtin_amdgcn_s_waitcnt(0);
    __syncthreads();

    long2v a2[4], b2[4];
#pragma unroll
    for (int mi = 0; mi < 4; ++mi) {
      int m = wm + mi * 16 + l16;
      a2[mi] = *(const long2v*)&As[(4 * m + (quad ^ ((m >> 1) & 3))) * 16];
    }
#pragma unroll
    for (int ni = 0; ni < 4; ++ni) {
      int n = wn + ni * 16 + l16;
      b2[ni] = *(const long2v*)&Bs[(4 * n + (quad ^ ((n >> 1) & 3))) * 16];
    }
#pragma unroll
    for (int h = 0; h < 2; ++h)
#pragma unroll
      for (int mi = 0; mi < 4; ++mi)
#pragma unroll
        for (int ni = 0; ni < 4; ++ni)
          acc[mi][ni] = __builtin_amdgcn_mfma_f32_16x16x32_fp8_fp8(
              a2[mi][h], b2[ni][h], acc[mi][ni], 0, 0, 0);
    __syncthreads();
  }

  // ---- epilogue: stage 128x128 fp8 tile in LDS (permk cols), linear stores ----
#pragma unroll
  for (int ni = 0; ni < 4; ++ni) {
    int col = wn + ni * 16 + l16;
    float bv = bias[bn + col];
    u32 pc = permk((u32)col);
#pragma unroll
    for (int mi = 0; mi < 4; ++mi) {
#pragma unroll
      for (int r = 0; r < 4; ++r) {
        int row = wm + mi * 16 + quad * 4 + r;
        float v = acc[mi][ni][r] * inv + bv;
        smem[row * 128 + pc] = f2fp8(fast_tanh(v) * outs);
      }
    }
  }
  __syncthreads();
#pragma unroll
  for (int j = 0; j < 4; ++j) {
    int u = j * 256 + t;                 // 1024 x 16B units
    int row = u >> 3, c16 = u & 7;
    *(long2v*)(C + (size_t)(bm + row) * N + bn + c16 * 16) =
        *(const long2v*)&smem[row * 128 + c16 * 16];
  }
}

// ---------- fp8 MFMA GEMM (256x256 tile, register read-ahead pipeline) ----------
// 512 threads = 8 waves (2M x 4N), per-wave 128x64 output. BK=64.
// DEPTH=4 LDS ring (128 KB), stage LEAD=2, ONE barrier per K-tile.
// Body(ti): stage(ti+2); vmcnt(4) [tile ti+1 complete]; s_barrier [visibility];
//   read B-frags(ti+1) into bnxt; MFMA cluster on tile ti, with A-frag(ti+1)
//   re-read into a2[mi] right after a2[mi]'s last use (WAR reuse, no extra regs).
// All frag-load latency for tile ti+1 hides under tile ti's MFMA cluster.
// SESSION VERDICT (rounds 3-9): this single-tile coarse body at VGPR=124 is
// the verified optimum. 16-wave (r4) and pair-phase (r6) spill acc to scratch
// (WRITE 131MB->250MB/1.35GB); fine 4-sub-phase body (r8/r9) wins 6us locally
// on GEMM5 but costs 10-19us elsewhere via co-compilation codegen coupling
// (rule #19). Do not widen; do not split. Best totals: 550.3/554.7us.
// Epilogue staged through LDS -> linear dwordx4 stores.
template <int EPI>
__global__ __launch_bounds__(512, 2) void gemm256(
    const u8* __restrict__ A, const u8* __restrict__ Bt,
    const float* __restrict__ bias, void* __restrict__ Cv,
    float inv, float outs, int M, int N, int K) {
  __shared__ __align__(16) u8 lds[4][2][256 * 64];   // ring: 128 KB; reused by epilogue
  const int t = threadIdx.x;
  const int wave = t >> 6, lane = t & 63;
  const int quad = lane >> 4, l16 = lane & 15;
  // XCD-aware swizzle (bijective: nwg % 8 == 0 for all our launches; guarded)
  const int nbx = N >> 8;
  const int nwg = nbx * (M >> 8);
  int raw = blockIdx.x + nbx * blockIdx.y;
  int wgid = ((nwg & 7) == 0) ? ((raw & 7) * (nwg >> 3) + (raw >> 3)) : raw;
  const int bm = (wgid / nbx) << 8, bn = (wgid % nbx) << 8;
  const int wm = (wave >> 2) * 128, wn = (wave & 3) * 64;
  const int nt = K >> 6;

  // stage K-tile ti into ring slot ti&3: 4 llds16/thread (vmcnt +4 per stage)
  auto stage = [&](int ti) {
    const int b = ti & 3;
    const int kt = ti << 6;
#pragma unroll
    for (int i = 0; i < 2; ++i) {
      int c = i * 512 + t;               // 0..1023 chunks of 16B
      int r = c >> 2, kcS = c & 3;
      int kc = kcS ^ ((r >> 1) & 3);
      llds16(A + (size_t)(bm + r) * K + kt + kc * 16, &lds[b][0][c * 16]);
    }
#pragma unroll
    for (int i = 0; i < 2; ++i) {
      int c = i * 512 + t;
      int r = c >> 2, kcS = c & 3;
      int kc = kcS ^ ((r >> 1) & 3);
      llds16(Bt + (size_t)(bn + r) * K + kt + kc * 16, &lds[b][1][c * 16]);
    }
  };

  // precomputed per-lane fragment byte offsets within a slot half
  int offA[8], offB[4];
#pragma unroll
  for (int mi = 0; mi < 8; ++mi) {
    int m = wm + mi * 16 + l16;
    offA[mi] = (4 * m + (quad ^ ((m >> 1) & 3))) * 16;
  }
#pragma unroll
  for (int ni = 0; ni < 4; ++ni) {
    int n = wn + ni * 16 + l16;
    offB[ni] = (4 * n + (quad ^ ((n >> 1) & 3))) * 16;
  }

  floatx4 acc[8][4];
#pragma unroll
  for (int i = 0; i < 8; ++i)
#pragma unroll
    for (int j = 0; j < 4; ++j) acc[i][j] = (floatx4){0.f, 0.f, 0.f, 0.f};

  long2v a2[8], b2[4], b3[4];

  // prologue: stage tiles 0,1; wait tile 0; load tile-0 fragments
  stage(0);
  stage(1);
  asm volatile("s_waitcnt vmcnt(4)" ::: "memory");
  __builtin_amdgcn_s_barrier();
  asm volatile("" ::: "memory");
  {
    const u8* bA = &lds[0][0][0];
    const u8* bB = &lds[0][1][0];
#pragma unroll
    for (int ni = 0; ni < 4; ++ni) b2[ni] = *(const long2v*)(bB + offB[ni]);
#pragma unroll
    for (int mi = 0; mi < 8; ++mi) a2[mi] = *(const long2v*)(bA + offA[mi]);
  }

#define GBODY(TI, BCUR, BNXT) {                                               \
    const int ti_ = (TI);                                                     \
    if (ti_ + 2 < nt) {                                                       \
      stage(ti_ + 2);                                                         \
      asm volatile("s_waitcnt vmcnt(4)" ::: "memory");                        \
    } else {                                                                  \
      asm volatile("s_waitcnt vmcnt(0)" ::: "memory");                        \
    }                                                                         \
    __builtin_amdgcn_s_barrier();                                             \
    asm volatile("" ::: "memory");                                            \
    const u8* bA_ = &lds[(ti_ + 1) & 3][0][0];                                \
    const u8* bB_ = &lds[(ti_ + 1) & 3][1][0];                                \
    _Pragma("unroll")                                                         \
    for (int ni = 0; ni < 4; ++ni) BNXT[ni] = *(const long2v*)(bB_ + offB[ni]);\
    __builtin_amdgcn_s_setprio(1);                                            \
    _Pragma("unroll")                                                         \
    for (int mi = 0; mi < 8; ++mi) {                                          \
      _Pragma("unroll")                                                       \
      for (int h = 0; h < 2; ++h)                                             \
        _Pragma("unroll")                                                     \
        for (int ni = 0; ni < 4; ++ni)                                        \
          acc[mi][ni] = __builtin_amdgcn_mfma_f32_16x16x32_fp8_fp8(           \
              a2[mi][h], BCUR[ni][h], acc[mi][ni], 0, 0, 0);                  \
      a2[mi] = *(const long2v*)(bA_ + offA[mi]);                              \
    }                                                                         \
    __builtin_amdgcn_s_setprio(0);                                            \
  }

  int ti = 0;
  for (; ti + 2 < nt; ti += 2) {        // nt is even (8 or 16)
    GBODY(ti, b2, b3);
    GBODY(ti + 1, b3, b2);
  }
  GBODY(ti, b2, b3);                    // ti == nt-2 (fills a2,b3 with tile nt-1)
#undef GBODY
  // peeled last K-tile: pure MFMA on a2 / b3
  __builtin_amdgcn_s_setprio(1);
#pragma unroll
  for (int mi = 0; mi < 8; ++mi)
#pragma unroll
    for (int h = 0; h < 2; ++h)
#pragma unroll
      for (int ni = 0; ni < 4; ++ni)
        acc[mi][ni] = __builtin_amdgcn_mfma_f32_16x16x32_fp8_fp8(
            a2[mi][h], b3[ni][h], acc[mi][ni], 0, 0, 0);
  __builtin_amdgcn_s_setprio(0);

  // ---- epilogue: stage full 256x256 tile in LDS, then linear stores ----
  __syncthreads();                       // all ring ds_reads retired block-wide
  u8* eb = &lds[0][0][0];                // 128 KB staging
  if (EPI == 0) {
    // fp8 out, permk cols applied at LDS write; 64 KB used
#pragma unroll
    for (int ni = 0; ni < 4; ++ni) {
      int col = wn + ni * 16 + l16;
      float bv = bias[bn + col];
      u32 pc = permk((u32)col);
#pragma unroll
      for (int mi = 0; mi < 8; ++mi) {
#pragma unroll
        for (int r = 0; r < 4; ++r) {
          int row = wm + mi * 16 + quad * 4 + r;
          float v = acc[mi][ni][r] * inv + bv;
          eb[row * 256 + pc] = f2fp8(fast_tanh(v) * outs);
        }
      }
    }
    __syncthreads();
#pragma unroll
    for (int j = 0; j < 8; ++j) {
      int u = j * 512 + t;               // 4096 x 16B units
      int row = u >> 4, c16 = u & 15;
      *(long2v*)((u8*)Cv + (size_t)(bm + row) * N + bn + c16 * 16) =
          *(const long2v*)&eb[row * 256 + c16 * 16];
    }
  } else {
    // bf16 out, natural cols; 128 KB used
    u16* ebw = (u16*)eb;
#pragma unroll
    for (int ni = 0; ni < 4; ++ni) {
      int col = wn + ni * 16 + l16;
      float bv = bias[bn + col];
#pragma unroll
      for (int mi = 0; mi < 8; ++mi) {
#pragma unroll
        for (int r = 0; r < 4; ++r) {
          int row = wm + mi * 16 + quad * 4 + r;
          float v = acc[mi][ni][r] * inv + bv;
          ebw[row * 256 + col] = f2bf(v);
        }
      }
    }
    __syncthreads();
#pragma unroll
    for (int j = 0; j < 16; ++j) {
      int u = j * 512 + t;               // 8192 x 16B units
      int row = u >> 5, c16 = u & 31;
      *(long2v*)((u16*)Cv + (size_t)(bm + row) * N + bn + c16 * 8) =
          *(const long2v*)&ebw[row * 256 + c16 * 8];
    }
  }
}

// ---------- fused GEMM23 + reparameterise + KL (fp8) ----------
// A: [M][K] fp8 (h*64, K permuted), Bt: [128][K] fp8, bias [128].
// Cols 0..63 = mu_z, 64..127 = lv_z. Writes z [M][permk(64)] fp8 (*16).
__global__ __launch_bounds__(256) void gemm_z(
    const u8* __restrict__ A, const u8* __restrict__ Bt,
    const float* __restrict__ bias, const float* __restrict__ eps,
    u8* __restrict__ z, float* __restrict__ accp, int M, int K) {
  __shared__ __align__(16) u8 As[128 * 64];
  __shared__ __align__(16) u8 Bs[128 * 64];
  __shared__ float sexp[128 * 64];   // exp(0.5*lv) staging [row][col]
  const int t = threadIdx.x;
  const int wave = t >> 6, lane = t & 63;
  const int quad = lane >> 4, l16 = lane & 15;
  const int bm = blockIdx.y * 128;
  const int wm = (wave >> 1) * 64, wn = (wave & 1) * 64;

  floatx4 acc[4][4];
#pragma unroll
  for (int i = 0; i < 4; ++i)
#pragma unroll
    for (int j = 0; j < 4; ++j) acc[i][j] = (floatx4){0.f, 0.f, 0.f, 0.f};

  for (int kt = 0; kt < K; kt += 64) {
#pragma unroll
    for (int i = 0; i < 2; ++i) {
      int c = i * 256 + t;
      int r = c >> 2, kcS = c & 3;
      int kc = kcS ^ ((r >> 1) & 3);
      llds16(A + (size_t)(bm + r) * K + kt + kc * 16, &As[c * 16]);
      llds16(Bt + (size_t)r * K + kt + kc * 16, &Bs[c * 16]);
    }
    __builtin_amdgcn_s_waitcnt(0);
    __syncthreads();

    long2v a2[4], b2[4];
#pragma unroll
    for (int mi = 0; mi < 4; ++mi) {
      int m = wm + mi * 16 + l16;
      a2[mi] = *(const long2v*)&As[(4 * m + (quad ^ ((m >> 1) & 3))) * 16];
    }
#pragma unroll
    for (int ni = 0; ni < 4; ++ni) {
      int n = wn + ni * 16 + l16;
      b2[ni] = *(const long2v*)&Bs[(4 * n + (quad ^ ((n >> 1) & 3))) * 16];
    }
#pragma unroll
    for (int h = 0; h < 2; ++h)
#pragma unroll
      for (int mi = 0; mi < 4; ++mi)
#pragma unroll
        for (int ni = 0; ni < 4; ++ni)
          acc[mi][ni] = __builtin_amdgcn_mfma_f32_16x16x32_fp8_fp8(
              a2[mi][h], b2[ni][h], acc[mi][ni], 0, 0, 0);
    __syncthreads();
  }

  const bool is_lv = (wave & 1);
  float kl = 0.f;
#pragma unroll
  for (int ni = 0; ni < 4; ++ni) {
    int col = wn + ni * 16 + l16;            // 0..127
    float bv = bias[col];
#pragma unroll
    for (int mi = 0; mi < 4; ++mi) {
#pragma unroll
      for (int r = 0; r < 4; ++r) {
        int row = wm + mi * 16 + quad * 4 + r;   // 0..127 local
        float v = acc[mi][ni][r] * INV_16384 + bv;
        if (is_lv) {
          kl += 1.0f + v - __expf(v);
          sexp[row * 64 + (col - 64)] = __expf(0.5f * v);
        } else {
          kl -= v * v;
        }
      }
    }
  }
  __syncthreads();
  if (!is_lv) {
#pragma unroll
    for (int ni = 0; ni < 4; ++ni) {
      int col = wn + ni * 16 + l16;          // 0..63
      float bv = bias[col];
#pragma unroll
      for (int mi = 0; mi < 4; ++mi) {
#pragma unroll
        for (int r = 0; r < 4; ++r) {
          int row = wm + mi * 16 + quad * 4 + r;
          float mu = acc[mi][ni][r] * INV_16384 + bv;
          size_t grow = (size_t)(bm + row);
          float ep = eps[grow * 64 + col];
          z[grow * 64 + permk(col)] = f2fp8((mu + sexp[row * 64 + col] * ep) * 16.f);
        }
      }
    }
  }
  kl *= 0.5f;
  for (int off = 32; off > 0; off >>= 1) kl += __shfl_xor(kl, off, 64);
  __shared__ float s4[4];
  if (lane == 0) s4[wave] = kl;
  __syncthreads();
  if (t == 0) atomicAdd(accp, s4[0] + s4[1] + s4[2] + s4[3]);
}

// ---------- softmax + diag-Gaussian log-likelihood ----------
// loglv: [B][1024] bf16 (0..511 logits, 512..1023 lv_x); x: [B][512] f32
__global__ __launch_bounds__(256) void lik_kernel(
    const u16* __restrict__ loglv, const float* __restrict__ x,
    float* __restrict__ acc) {
  typedef __attribute__((ext_vector_type(8))) short short8;
  const int wave = threadIdx.x >> 6, lane = threadIdx.x & 63;
  float wacc = 0.f;
  for (int rr = 0; rr < 8; ++rr) {
    int row = blockIdx.x * 32 + wave * 8 + rr;
    const u16* Lr = loglv + (size_t)row * 1024;
    short8 lg8 = ((const short8*)Lr)[lane];
    float lg[8];
#pragma unroll
    for (int j = 0; j < 8; ++j) lg[j] = bf2f((u16)lg8[j]);
    float mx = lg[0];
#pragma unroll
    for (int j = 1; j < 8; ++j) mx = fmaxf(mx, lg[j]);
    for (int off = 32; off > 0; off >>= 1) mx = fmaxf(mx, __shfl_xor(mx, off, 64));
    float e[8], s = 0.f;
#pragma unroll
    for (int j = 0; j < 8; ++j) { e[j] = __expf(lg[j] - mx); s += e[j]; }
    for (int off = 32; off > 0; off >>= 1) s += __shfl_xor(s, off, 64);
    float inv_s = 1.0f / s;
    short8 lv8 = ((const short8*)Lr)[64 + lane];
    const float* xr = x + (size_t)row * 512 + lane * 8;
    float4 x0 = *(const float4*)xr, x1 = *(const float4*)(xr + 4);
    float xs[8] = {x0.x, x0.y, x0.z, x0.w, x1.x, x1.y, x1.z, x1.w};
    float T = 0.f;
#pragma unroll
    for (int j = 0; j < 8; ++j) {
      float lv = bf2f((u16)lv8[j]);
      float d = xs[j] - e[j] * inv_s;
      T += lv + d * d * __expf(-lv) + LOG2PI_F;
    }
    for (int off = 32; off > 0; off >>= 1) T += __shfl_xor(T, off, 64);
    if (lane == 0) wacc += -0.5f * T;
  }
  __shared__ float s4[4];
  if (lane == 0) s4[wave] = wacc;
  __syncthreads();
  if (threadIdx.x == 0) atomicAdd(acc, s4[0] + s4[1] + s4[2] + s4[3]);
}

__global__ void fin_kernel(const float* __restrict__ acc, float* __restrict__ out) {
  out[0] = acc[0] * (1.0f / 65536.0f);
}

// ---------- launch ----------
extern "C" void kernel_launch(void* const* d_in, const int* in_sizes, int n_in,
                              void* d_out, int out_size, void* d_ws, size_t ws_size,
                              hipStream_t stream) {
  const int B = 65536, D = 512, H = 1024, L = 64;
  const float* x       = (const float*)d_in[0];
  const float* eps     = (const float*)d_in[1];
  const float* W_enc_h = (const float*)d_in[2];
  const float* b_enc_h = (const float*)d_in[3];
  const float* W_enc_mu= (const float*)d_in[4];
  const float* b_enc_mu= (const float*)d_in[5];
  const float* W_enc_lv= (const float*)d_in[6];
  const float* b_enc_lv= (const float*)d_in[7];
  const float* W_dec_h = (const float*)d_in[8];
  const float* b_dec_h = (const float*)d_in[9];
  const float* W_dec_mu= (const float*)d_in[10];
  const float* b_dec_mu= (const float*)d_in[11];
  const float* W_dec_lv= (const float*)d_in[12];
  const float* b_dec_lv= (const float*)d_in[13];

  char* ws = (char*)d_ws;
  // weights (fp8) / bias / acc block
  u8*   Wt_eh  = (u8*)(ws + 0);             // [1024][512]  512K
  u8*   Wt_z   = (u8*)(ws + 524288);        // [128][1024]  128K
  u8*   Wt_dh  = (u8*)(ws + 655360);        // [1024][64]    64K
  u8*   Wt_dx  = (u8*)(ws + 720896);        // [1024][1024]   1M
  float* bh    = (float*)(ws + 2097152);    // [1024]
  float* bz    = (float*)(ws + 2101248);    // [128]
  float* bdh   = (float*)(ws + 2105344);    // [1024]
  float* bdx   = (float*)(ws + 2109440);    // [1024]
  float* acc   = (float*)(ws + 2113536);    // [1]
  // big regions (peak 232 MB)
  u8*   hbuf   = (u8*)(ws + 4194304);       // [B][1024] fp8: h then hd (64MB)
  u8*   xb     = (u8*)(ws + 71303168);      // [B][512] fp8 (32MB, dead after GEMM1)
  u8*   zbuf   = (u8*)(ws + 104857600);     // [B][64] fp8 (4MB, dead after GEMM4)
  u16*  loglv  = (u16*)(ws + 109051904);    // [B][1024] bf16 (128MB)

  hipMemsetAsync(acc, 0, 256, stream);

  // ---- packing ----
  pack_xb<<<(B * D / 4 + 255) / 256, 256, 0, stream>>>(x, (u32*)xb, B * D / 4);
  pack_wt<<<(D * H + 255) / 256, 256, 0, stream>>>(W_enc_h, Wt_eh, D, H);
  pack_wt2<<<(H * 2 * L + 255) / 256, 256, 0, stream>>>(W_enc_mu, W_enc_lv, Wt_z, H, L, L);
  pack_wt<<<(L * H + 255) / 256, 256, 0, stream>>>(W_dec_h, Wt_dh, L, H);
  pack_wt2<<<(H * 2 * D + 255) / 256, 256, 0, stream>>>(W_dec_mu, W_dec_lv, Wt_dx, H, D, D);
  catf<<<(H + 255) / 256, 256, 0, stream>>>(b_enc_h, b_enc_h, bh, H, 0);
  catf<<<(2 * L + 255) / 256, 256, 0, stream>>>(b_enc_mu, b_enc_lv, bz, L, L);
  catf<<<(H + 255) / 256, 256, 0, stream>>>(b_dec_h, b_dec_h, bdh, H, 0);
  catf<<<(2 * D + 255) / 256, 256, 0, stream>>>(b_dec_mu, b_dec_lv, bdx, D, D);

  // ---- encoder: h = tanh(x @ W_enc_h + b), h stored fp8*64, K-permuted ----
  gemm256<0><<<dim3(H / 256, B / 256), 512, 0, stream>>>(
      xb, Wt_eh, bh, hbuf, INV_4096, 64.f, B, H, D);
  // ---- fused: mu|lv = h @ Wt_z + b ; z = mu + exp(.5 lv) eps (fp8*16) ; KL ----
  gemm_z<<<dim3(1, B / 128), 256, 0, stream>>>(hbuf, Wt_z, bz, eps, zbuf, acc, B, H);
  // ---- decoder hidden: hd = tanh(z @ W_dec_h + b), fp8*64 (K=64: 128^2 kernel) ----
  gemm_bt0<<<dim3(H / 128, B / 128), 256, 0, stream>>>(
      zbuf, Wt_dh, bdh, hbuf, INV_4096, 64.f, B, H, L);
  // ---- logits | lv_x = hd @ [W_dec_mu|W_dec_lv] + b -> bf16 (natural col order) ----
  gemm256<2><<<dim3(1024 / 256, B / 256), 512, 0, stream>>>(
      hbuf, Wt_dx, bdx, loglv, INV_16384, 0.f, B, 1024, H);
  // ---- softmax + log-likelihood ----
  lik_kernel<<<B / 32, 256, 0, stream>>>(loglv, x, acc);
  // ---- finalize mean ----
  fin_kernel<<<1, 1, 0, stream>>>(acc, (float*)d_out);
}

// Round 11
// 548.292 us; speedup vs baseline: 1.0268x; 1.0053x over previous
//
#include <hip/hip_runtime.h>

typedef unsigned char u8;
typedef unsigned short u16;
typedef unsigned int u32;
typedef unsigned long long u64;
typedef long i64;
typedef __attribute__((ext_vector_type(2))) long long2v;
typedef __attribute__((ext_vector_type(4))) float floatx4;

#define LOG2PI_F 1.8378770664093453f

// ---------- helpers ----------
__device__ __forceinline__ u16 f2bf(float f) {
  union { float f; u32 i; } c; c.f = f;
  u32 i = c.i;
  u32 r = (i + 0x7fffu + ((i >> 16) & 1u)) >> 16;   // RNE (inputs finite)
  return (u16)r;
}
__device__ __forceinline__ float bf2f(u16 u) {
  union { u32 i; float f; } c; c.i = ((u32)u) << 16; return c.f;
}
__device__ __forceinline__ u8 f2fp8(float f) {
  int p = __builtin_amdgcn_cvt_pk_fp8_f32(f, f, 0, false);
  return (u8)(p & 0xff);
}
__device__ __forceinline__ u32 pk4fp8(float a, float b, float c, float d) {
  int lo = __builtin_amdgcn_cvt_pk_fp8_f32(a, b, 0, false);
  int v  = __builtin_amdgcn_cvt_pk_fp8_f32(c, d, lo, true);
  return (u32)v;
}
// manual e4m3fn decode of byte b of word w (no builtin dependency):
// normal: 2^(e-7)*(1+m/8)  -> f32 bits ((e+120)<<23)|(m<<20); subnormal: m*2^-9.
__device__ __forceinline__ float fp82f(u32 w, int b) {
  u32 v = (w >> (b * 8)) & 0xffu;
  u32 e = (v >> 3) & 15u, m = v & 7u;
  union { u32 i; float f; } c;
  c.i = ((e + 120u) << 23) | (m << 20);
  float f = (e == 0u) ? (float)m * 0.001953125f : c.f;
  return (v & 0x80u) ? -f : f;
}
// fast tanh: (t-1)/(t+1), t=exp(2x). 1-ulp-ish, swamped by fp8 quantization.
// clamp avoids inf*0=NaN; tanh(10)=1-4e-9 == 1.0f in fp8.
__device__ __forceinline__ float fast_tanh(float x) {
  float xc = fminf(fmaxf(x, -10.f), 10.f);
  float t = __expf(2.f * xc);
  return (t - 1.f) * __builtin_amdgcn_rcpf(t + 1.f);
}
__device__ __forceinline__ void llds16(const void* g, void* l) {
  __builtin_amdgcn_global_load_lds(
      (const __attribute__((address_space(1))) u32*)g,
      (__attribute__((address_space(3))) u32*)l, 16, 0, 0);
}
// K-storage permutation: per 64-k group, octet order O0,O4,O1,O5,O2,O6,O3,O7
// so (h0,h1) octet pairs for quad q are the two 8B halves of 16B chunk q.
__device__ __forceinline__ u32 permk(u32 k) {
  u32 g = k & ~63u, o = (k >> 3) & 7u, r = k & 7u;
  u32 po = ((o & 3u) << 1) | (o >> 2);
  return g | (po << 3) | r;
}

// Scales (powers of 2; keep e4m3 out of subnormals):
//   x*16, weights*256, tanh-activations*64, z*16, loglv*16. Inverses folded.
#define INV_4096  2.44140625e-4f
#define INV_16384 6.103515625e-5f

// ---------- packing kernels ----------
__global__ void pack_xb(const float* __restrict__ in, u32* __restrict__ out, int n4) {
  int i = blockIdx.x * 256 + threadIdx.x;
  if (i >= n4) return;
  const float4 v = ((const float4*)in)[i];
  int row = i >> 7;                    // D/4 = 128
  int k = (i & 127) << 2;
  int kp = permk(k);                   // float4 stays inside one octet
  out[(row << 7) + (kp >> 2)] = pk4fp8(v.x * 16.f, v.y * 16.f, v.z * 16.f, v.w * 16.f);
}

// W [K][N] fp32 -> Wt [N][permk(K)] fp8 (*256)
__global__ void pack_wt(const float* __restrict__ W, u8* __restrict__ Wt, int K, int N) {
  int idx = blockIdx.x * 256 + threadIdx.x;
  if (idx >= K * N) return;
  int k = idx / N, n = idx - k * N;
  Wt[(size_t)n * K + permk(k)] = f2fp8(W[idx] * 256.f);
}

// W1 [K][N1], W2 [K][N2] fp32 -> Wt [(N1+N2)][permk(K)] fp8 (*256)
__global__ void pack_wt2(const float* __restrict__ W1, const float* __restrict__ W2,
                         u8* __restrict__ Wt, int K, int N1, int N2) {
  int idx = blockIdx.x * 256 + threadIdx.x;
  if (idx >= (N1 + N2) * K) return;
  int n = idx / K, k = idx - n * K;
  float v = (n < N1) ? W1[(size_t)k * N1 + n] : W2[(size_t)k * N2 + (n - N1)];
  Wt[(size_t)n * K + permk(k)] = f2fp8(v * 256.f);
}

__global__ void catf(const float* __restrict__ a, const float* __restrict__ b,
                     float* __restrict__ o, int n1, int n2) {
  int i = blockIdx.x * 256 + threadIdx.x;
  if (i < n1) o[i] = a[i];
  else if (i < n1 + n2) o[i] = b[i - n1];
}

// ---------- fp8 MFMA GEMM, 128x128 tile (GEMM4 only: K=64, single K-tile) ----------
// A: [M][K] fp8 (K permuted), Bt: [N][K] fp8 (K permuted), bias: [N] f32.
// Epilogue: fast_tanh -> fp8*outs, staged through LDS (permk applied there), then
// fully-linear dwordx4 global stores (no write amplification).
__global__ __launch_bounds__(256) void gemm_bt0(
    const u8* __restrict__ A, const u8* __restrict__ Bt,
    const float* __restrict__ bias, u8* __restrict__ C,
    float inv, float outs, int M, int N, int K) {
  __shared__ __align__(16) u8 smem[16384];
  u8* As = smem;
  u8* Bs = smem + 8192;
  const int t = threadIdx.x;
  const int wave = t >> 6, lane = t & 63;
  const int quad = lane >> 4, l16 = lane & 15;
  const int bm = blockIdx.y * 128, bn = blockIdx.x * 128;
  const int wm = (wave >> 1) * 64, wn = (wave & 1) * 64;

  floatx4 acc[4][4];
#pragma unroll
  for (int i = 0; i < 4; ++i)
#pragma unroll
    for (int j = 0; j < 4; ++j) acc[i][j] = (floatx4){0.f, 0.f, 0.f, 0.f};

  for (int kt = 0; kt < K; kt += 64) {
#pragma unroll
    for (int i = 0; i < 2; ++i) {
      int c = i * 256 + t;
      int r = c >> 2, kcS = c & 3;
      int kc = kcS ^ ((r >> 1) & 3);
      llds16(A + (size_t)(bm + r) * K + kt + kc * 16, &As[c * 16]);
      llds16(Bt + (size_t)(bn + r) * K + kt + kc * 16, &Bs[c * 16]);
    }
    __builtin_amdgcn_s_waitcnt(0);
    __syncthreads();

    long2v a2[4], b2[4];
#pragma unroll
    for (int mi = 0; mi < 4; ++mi) {
      int m = wm + mi * 16 + l16;
      a2[mi] = *(const long2v*)&As[(4 * m + (quad ^ ((m >> 1) & 3))) * 16];
    }
#pragma unroll
    for (int ni = 0; ni < 4; ++ni) {
      int n = wn + ni * 16 + l16;
      b2[ni] = *(const long2v*)&Bs[(4 * n + (quad ^ ((n >> 1) & 3))) * 16];
    }
#pragma unroll
    for (int h = 0; h < 2; ++h)
#pragma unroll
      for (int mi = 0; mi < 4; ++mi)
#pragma unroll
        for (int ni = 0; ni < 4; ++ni)
          acc[mi][ni] = __builtin_amdgcn_mfma_f32_16x16x32_fp8_fp8(
              a2[mi][h], b2[ni][h], acc[mi][ni], 0, 0, 0);
    __syncthreads();
  }

  // ---- epilogue: stage 128x128 fp8 tile in LDS (permk cols), linear stores ----
#pragma unroll
  for (int ni = 0; ni < 4; ++ni) {
    int col = wn + ni * 16 + l16;
    float bv = bias[bn + col];
    u32 pc = permk((u32)col);
#pragma unroll
    for (int mi = 0; mi < 4; ++mi) {
#pragma unroll
      for (int r = 0; r < 4; ++r) {
        int row = wm + mi * 16 + quad * 4 + r;
        float v = acc[mi][ni][r] * inv + bv;
        smem[row * 128 + pc] = f2fp8(fast_tanh(v) * outs);
      }
    }
  }
  __syncthreads();
#pragma unroll
  for (int j = 0; j < 4; ++j) {
    int u = j * 256 + t;                 // 1024 x 16B units
    int row = u >> 3, c16 = u & 7;
    *(long2v*)(C + (size_t)(bm + row) * N + bn + c16 * 16) =
        *(const long2v*)&smem[row * 128 + c16 * 16];
  }
}

// ---------- fp8 MFMA GEMM (256x256 tile, register read-ahead pipeline) ----------
// 512 threads = 8 waves (2M x 4N), per-wave 128x64 output. BK=64.
// DEPTH=4 LDS ring (128 KB), stage LEAD=2, ONE barrier per K-tile.
// Body(ti): stage(ti+2); vmcnt(4) [tile ti+1 complete]; s_barrier [visibility];
//   read B-frags(ti+1) into bnxt; MFMA cluster on tile ti, with A-frag(ti+1)
//   re-read into a2[mi] right after a2[mi]'s last use (WAR reuse, no extra regs).
// SESSION VERDICT (rounds 3-10): this single-tile coarse body at VGPR=124 is
// the verified optimum. 16-wave (r4) and pair-phase (r6) spill acc to scratch;
// fine 4-sub-phase body (r8/r9) wins 6us locally but costs 10-19us elsewhere
// via co-compilation codegen coupling (rule #19). K-loop bank conflicts are
// 2048 cyc/block = 0.8% (not a lever). Do not widen; do not split.
// ROUND-11 CHANGE: EPI=2 output is now fp8*outs at NATURAL cols (u8), halving
// loglv HBM traffic (write 128->64 MB; lik read 128->64 MB). K-loop untouched.
// Epilogue staged through LDS -> linear dwordx4 stores.
template <int EPI>
__global__ __launch_bounds__(512, 2) void gemm256(
    const u8* __restrict__ A, const u8* __restrict__ Bt,
    const float* __restrict__ bias, void* __restrict__ Cv,
    float inv, float outs, int M, int N, int K) {
  __shared__ __align__(16) u8 lds[4][2][256 * 64];   // ring: 128 KB; reused by epilogue
  const int t = threadIdx.x;
  const int wave = t >> 6, lane = t & 63;
  const int quad = lane >> 4, l16 = lane & 15;
  // XCD-aware swizzle (bijective: nwg % 8 == 0 for all our launches; guarded)
  const int nbx = N >> 8;
  const int nwg = nbx * (M >> 8);
  int raw = blockIdx.x + nbx * blockIdx.y;
  int wgid = ((nwg & 7) == 0) ? ((raw & 7) * (nwg >> 3) + (raw >> 3)) : raw;
  const int bm = (wgid / nbx) << 8, bn = (wgid % nbx) << 8;
  const int wm = (wave >> 2) * 128, wn = (wave & 3) * 64;
  const int nt = K >> 6;

  // stage K-tile ti into ring slot ti&3: 4 llds16/thread (vmcnt +4 per stage)
  auto stage = [&](int ti) {
    const int b = ti & 3;
    const int kt = ti << 6;
#pragma unroll
    for (int i = 0; i < 2; ++i) {
      int c = i * 512 + t;               // 0..1023 chunks of 16B
      int r = c >> 2, kcS = c & 3;
      int kc = kcS ^ ((r >> 1) & 3);
      llds16(A + (size_t)(bm + r) * K + kt + kc * 16, &lds[b][0][c * 16]);
    }
#pragma unroll
    for (int i = 0; i < 2; ++i) {
      int c = i * 512 + t;
      int r = c >> 2, kcS = c & 3;
      int kc = kcS ^ ((r >> 1) & 3);
      llds16(Bt + (size_t)(bn + r) * K + kt + kc * 16, &lds[b][1][c * 16]);
    }
  };

  // precomputed per-lane fragment byte offsets within a slot half
  int offA[8], offB[4];
#pragma unroll
  for (int mi = 0; mi < 8; ++mi) {
    int m = wm + mi * 16 + l16;
    offA[mi] = (4 * m + (quad ^ ((m >> 1) & 3))) * 16;
  }
#pragma unroll
  for (int ni = 0; ni < 4; ++ni) {
    int n = wn + ni * 16 + l16;
    offB[ni] = (4 * n + (quad ^ ((n >> 1) & 3))) * 16;
  }

  floatx4 acc[8][4];
#pragma unroll
  for (int i = 0; i < 8; ++i)
#pragma unroll
    for (int j = 0; j < 4; ++j) acc[i][j] = (floatx4){0.f, 0.f, 0.f, 0.f};

  long2v a2[8], b2[4], b3[4];

  // prologue: stage tiles 0,1; wait tile 0; load tile-0 fragments
  stage(0);
  stage(1);
  asm volatile("s_waitcnt vmcnt(4)" ::: "memory");
  __builtin_amdgcn_s_barrier();
  asm volatile("" ::: "memory");
  {
    const u8* bA = &lds[0][0][0];
    const u8* bB = &lds[0][1][0];
#pragma unroll
    for (int ni = 0; ni < 4; ++ni) b2[ni] = *(const long2v*)(bB + offB[ni]);
#pragma unroll
    for (int mi = 0; mi < 8; ++mi) a2[mi] = *(const long2v*)(bA + offA[mi]);
  }

#define GBODY(TI, BCUR, BNXT) {                                               \
    const int ti_ = (TI);                                                     \
    if (ti_ + 2 < nt) {                                                       \
      stage(ti_ + 2);                                                         \
      asm volatile("s_waitcnt vmcnt(4)" ::: "memory");                        \
    } else {                                                                  \
      asm volatile("s_waitcnt vmcnt(0)" ::: "memory");                        \
    }                                                                         \
    __builtin_amdgcn_s_barrier();                                             \
    asm volatile("" ::: "memory");                                            \
    const u8* bA_ = &lds[(ti_ + 1) & 3][0][0];                                \
    const u8* bB_ = &lds[(ti_ + 1) & 3][1][0];                                \
    _Pragma("unroll")                                                         \
    for (int ni = 0; ni < 4; ++ni) BNXT[ni] = *(const long2v*)(bB_ + offB[ni]);\
    __builtin_amdgcn_s_setprio(1);                                            \
    _Pragma("unroll")                                                         \
    for (int mi = 0; mi < 8; ++mi) {                                          \
      _Pragma("unroll")                                                       \
      for (int h = 0; h < 2; ++h)                                             \
        _Pragma("unroll")                                                     \
        for (int ni = 0; ni < 4; ++ni)                                        \
          acc[mi][ni] = __builtin_amdgcn_mfma_f32_16x16x32_fp8_fp8(           \
              a2[mi][h], BCUR[ni][h], acc[mi][ni], 0, 0, 0);                  \
      a2[mi] = *(const long2v*)(bA_ + offA[mi]);                              \
    }                                                                         \
    __builtin_amdgcn_s_setprio(0);                                            \
  }

  int ti = 0;
  for (; ti + 2 < nt; ti += 2) {        // nt is even (8 or 16)
    GBODY(ti, b2, b3);
    GBODY(ti + 1, b3, b2);
  }
  GBODY(ti, b2, b3);                    // ti == nt-2 (fills a2,b3 with tile nt-1)
#undef GBODY
  // peeled last K-tile: pure MFMA on a2 / b3
  __builtin_amdgcn_s_setprio(1);
#pragma unroll
  for (int mi = 0; mi < 8; ++mi)
#pragma unroll
    for (int h = 0; h < 2; ++h)
#pragma unroll
      for (int ni = 0; ni < 4; ++ni)
        acc[mi][ni] = __builtin_amdgcn_mfma_f32_16x16x32_fp8_fp8(
            a2[mi][h], b3[ni][h], acc[mi][ni], 0, 0, 0);
  __builtin_amdgcn_s_setprio(0);

  // ---- epilogue: stage full 256x256 fp8 tile in LDS, then linear stores ----
  __syncthreads();                       // all ring ds_reads retired block-wide
  u8* eb = &lds[0][0][0];                // 64 KB staging
  if (EPI == 0) {
    // tanh -> fp8*outs, permk cols applied at LDS write
#pragma unroll
    for (int ni = 0; ni < 4; ++ni) {
      int col = wn + ni * 16 + l16;
      float bv = bias[bn + col];
      u32 pc = permk((u32)col);
#pragma unroll
      for (int mi = 0; mi < 8; ++mi) {
#pragma unroll
        for (int r = 0; r < 4; ++r) {
          int row = wm + mi * 16 + quad * 4 + r;
          float v = acc[mi][ni][r] * inv + bv;
          eb[row * 256 + pc] = f2fp8(fast_tanh(v) * outs);
        }
      }
    }
  } else {
    // plain -> fp8*outs at NATURAL cols (loglv path; lik decodes *1/outs)
#pragma unroll
    for (int ni = 0; ni < 4; ++ni) {
      int col = wn + ni * 16 + l16;
      float bv = bias[bn + col];
#pragma unroll
      for (int mi = 0; mi < 8; ++mi) {
#pragma unroll
        for (int r = 0; r < 4; ++r) {
          int row = wm + mi * 16 + quad * 4 + r;
          float v = acc[mi][ni][r] * inv + bv;
          eb[row * 256 + col] = f2fp8(v * outs);
        }
      }
    }
  }
  __syncthreads();
#pragma unroll
  for (int j = 0; j < 8; ++j) {
    int u = j * 512 + t;                 // 4096 x 16B units
    int row = u >> 4, c16 = u & 15;
    *(long2v*)((u8*)Cv + (size_t)(bm + row) * N + bn + c16 * 16) =
        *(const long2v*)&eb[row * 256 + c16 * 16];
  }
}

// ---------- fused GEMM23 + reparameterise + KL (fp8) ----------
// A: [M][K] fp8 (h*64, K permuted), Bt: [128][K] fp8, bias [128].
// Cols 0..63 = mu_z, 64..127 = lv_z. Writes z [M][permk(64)] fp8 (*16).
__global__ __launch_bounds__(256) void gemm_z(
    const u8* __restrict__ A, const u8* __restrict__ Bt,
    const float* __restrict__ bias, const float* __restrict__ eps,
    u8* __restrict__ z, float* __restrict__ accp, int M, int K) {
  __shared__ __align__(16) u8 As[128 * 64];
  __shared__ __align__(16) u8 Bs[128 * 64];
  __shared__ float sexp[128 * 64];   // exp(0.5*lv) staging [row][col]
  const int t = threadIdx.x;
  const int wave = t >> 6, lane = t & 63;
  const int quad = lane >> 4, l16 = lane & 15;
  const int bm = blockIdx.y * 128;
  const int wm = (wave >> 1) * 64, wn = (wave & 1) * 64;

  floatx4 acc[4][4];
#pragma unroll
  for (int i = 0; i < 4; ++i)
#pragma unroll
    for (int j = 0; j < 4; ++j) acc[i][j] = (floatx4){0.f, 0.f, 0.f, 0.f};

  for (int kt = 0; kt < K; kt += 64) {
#pragma unroll
    for (int i = 0; i < 2; ++i) {
      int c = i * 256 + t;
      int r = c >> 2, kcS = c & 3;
      int kc = kcS ^ ((r >> 1) & 3);
      llds16(A + (size_t)(bm + r) * K + kt + kc * 16, &As[c * 16]);
      llds16(Bt + (size_t)r * K + kt + kc * 16, &Bs[c * 16]);
    }
    __builtin_amdgcn_s_waitcnt(0);
    __syncthreads();

    long2v a2[4], b2[4];
#pragma unroll
    for (int mi = 0; mi < 4; ++mi) {
      int m = wm + mi * 16 + l16;
      a2[mi] = *(const long2v*)&As[(4 * m + (quad ^ ((m >> 1) & 3))) * 16];
    }
#pragma unroll
    for (int ni = 0; ni < 4; ++ni) {
      int n = wn + ni * 16 + l16;
      b2[ni] = *(const long2v*)&Bs[(4 * n + (quad ^ ((n >> 1) & 3))) * 16];
    }
#pragma unroll
    for (int h = 0; h < 2; ++h)
#pragma unroll
      for (int mi = 0; mi < 4; ++mi)
#pragma unroll
        for (int ni = 0; ni < 4; ++ni)
          acc[mi][ni] = __builtin_amdgcn_mfma_f32_16x16x32_fp8_fp8(
              a2[mi][h], b2[ni][h], acc[mi][ni], 0, 0, 0);
    __syncthreads();
  }

  const bool is_lv = (wave & 1);
  float kl = 0.f;
#pragma unroll
  for (int ni = 0; ni < 4; ++ni) {
    int col = wn + ni * 16 + l16;            // 0..127
    float bv = bias[col];
#pragma unroll
    for (int mi = 0; mi < 4; ++mi) {
#pragma unroll
      for (int r = 0; r < 4; ++r) {
        int row = wm + mi * 16 + quad * 4 + r;   // 0..127 local
        float v = acc[mi][ni][r] * INV_16384 + bv;
        if (is_lv) {
          kl += 1.0f + v - __expf(v);
          sexp[row * 64 + (col - 64)] = __expf(0.5f * v);
        } else {
          kl -= v * v;
        }
      }
    }
  }
  __syncthreads();
  if (!is_lv) {
#pragma unroll
    for (int ni = 0; ni < 4; ++ni) {
      int col = wn + ni * 16 + l16;          // 0..63
      float bv = bias[col];
#pragma unroll
      for (int mi = 0; mi < 4; ++mi) {
#pragma unroll
        for (int r = 0; r < 4; ++r) {
          int row = wm + mi * 16 + quad * 4 + r;
          float mu = acc[mi][ni][r] * INV_16384 + bv;
          size_t grow = (size_t)(bm + row);
          float ep = eps[grow * 64 + col];
          z[grow * 64 + permk(col)] = f2fp8((mu + sexp[row * 64 + col] * ep) * 16.f);
        }
      }
    }
  }
  kl *= 0.5f;
  for (int off = 32; off > 0; off >>= 1) kl += __shfl_xor(kl, off, 64);
  __shared__ float s4[4];
  if (lane == 0) s4[wave] = kl;
  __syncthreads();
  if (t == 0) atomicAdd(accp, s4[0] + s4[1] + s4[2] + s4[3]);
}

// ---------- softmax + diag-Gaussian log-likelihood ----------
// loglv: [B][1024] fp8*16 (0..511 logits, 512..1023 lv_x); x: [B][512] f32
__global__ __launch_bounds__(256) void lik_kernel(
    const u8* __restrict__ loglv, const float* __restrict__ x,
    float* __restrict__ acc) {
  const int wave = threadIdx.x >> 6, lane = threadIdx.x & 63;
  float wacc = 0.f;
  for (int rr = 0; rr < 8; ++rr) {
    int row = blockIdx.x * 32 + wave * 8 + rr;
    const u8* Lr = loglv + (size_t)row * 1024;
    u64 lgw = ((const u64*)Lr)[lane];          // 8 fp8 logits (*16)
    float lg[8];
#pragma unroll
    for (int j = 0; j < 8; ++j)
      lg[j] = fp82f((u32)(lgw >> (32 * (j >> 2))), j & 3) * 0.0625f;
    float mx = lg[0];
#pragma unroll
    for (int j = 1; j < 8; ++j) mx = fmaxf(mx, lg[j]);
    for (int off = 32; off > 0; off >>= 1) mx = fmaxf(mx, __shfl_xor(mx, off, 64));
    float e[8], s = 0.f;
#pragma unroll
    for (int j = 0; j < 8; ++j) { e[j] = __expf(lg[j] - mx); s += e[j]; }
    for (int off = 32; off > 0; off >>= 1) s += __shfl_xor(s, off, 64);
    float inv_s = 1.0f / s;
    u64 lvw = ((const u64*)Lr)[64 + lane];     // 8 fp8 lv_x (*16)
    const float* xr = x + (size_t)row * 512 + lane * 8;
    float4 x0 = *(const float4*)xr, x1 = *(const float4*)(xr + 4);
    float xs[8] = {x0.x, x0.y, x0.z, x0.w, x1.x, x1.y, x1.z, x1.w};
    float T = 0.f;
#pragma unroll
    for (int j = 0; j < 8; ++j) {
      float lv = fp82f((u32)(lvw >> (32 * (j >> 2))), j & 3) * 0.0625f;
      float d = xs[j] - e[j] * inv_s;
      T += lv + d * d * __expf(-lv) + LOG2PI_F;
    }
    for (int off = 32; off > 0; off >>= 1) T += __shfl_xor(T, off, 64);
    if (lane == 0) wacc += -0.5f * T;
  }
  __shared__ float s4[4];
  if (lane == 0) s4[wave] = wacc;
  __syncthreads();
  if (threadIdx.x == 0) atomicAdd(acc, s4[0] + s4[1] + s4[2] + s4[3]);
}

__global__ void fin_kernel(const float* __restrict__ acc, float* __restrict__ out) {
  out[0] = acc[0] * (1.0f / 65536.0f);
}

// ---------- launch ----------
extern "C" void kernel_launch(void* const* d_in, const int* in_sizes, int n_in,
                              void* d_out, int out_size, void* d_ws, size_t ws_size,
                              hipStream_t stream) {
  const int B = 65536, D = 512, H = 1024, L = 64;
  const float* x       = (const float*)d_in[0];
  const float* eps     = (const float*)d_in[1];
  const float* W_enc_h = (const float*)d_in[2];
  const float* b_enc_h = (const float*)d_in[3];
  const float* W_enc_mu= (const float*)d_in[4];
  const float* b_enc_mu= (const float*)d_in[5];
  const float* W_enc_lv= (const float*)d_in[6];
  const float* b_enc_lv= (const float*)d_in[7];
  const float* W_dec_h = (const float*)d_in[8];
  const float* b_dec_h = (const float*)d_in[9];
  const float* W_dec_mu= (const float*)d_in[10];
  const float* b_dec_mu= (const float*)d_in[11];
  const float* W_dec_lv= (const float*)d_in[12];
  const float* b_dec_lv= (const float*)d_in[13];

  char* ws = (char*)d_ws;
  // weights (fp8) / bias / acc block
  u8*   Wt_eh  = (u8*)(ws + 0);             // [1024][512]  512K
  u8*   Wt_z   = (u8*)(ws + 524288);        // [128][1024]  128K
  u8*   Wt_dh  = (u8*)(ws + 655360);        // [1024][64]    64K
  u8*   Wt_dx  = (u8*)(ws + 720896);        // [1024][1024]   1M
  float* bh    = (float*)(ws + 2097152);    // [1024]
  float* bz    = (float*)(ws + 2101248);    // [128]
  float* bdh   = (float*)(ws + 2105344);    // [1024]
  float* bdx   = (float*)(ws + 2109440);    // [1024]
  float* acc   = (float*)(ws + 2113536);    // [1]
  // big regions
  u8*   hbuf   = (u8*)(ws + 4194304);       // [B][1024] fp8: h then hd (64MB)
  u8*   xb     = (u8*)(ws + 71303168);      // [B][512] fp8 (32MB, dead after GEMM1)
  u8*   zbuf   = (u8*)(ws + 104857600);     // [B][64] fp8 (4MB, dead after GEMM4)
  u8*   loglv  = (u8*)(ws + 109051904);     // [B][1024] fp8*16 (64MB)

  hipMemsetAsync(acc, 0, 256, stream);

  // ---- packing ----
  pack_xb<<<(B * D / 4 + 255) / 256, 256, 0, stream>>>(x, (u32*)xb, B * D / 4);
  pack_wt<<<(D * H + 255) / 256, 256, 0, stream>>>(W_enc_h, Wt_eh, D, H);
  pack_wt2<<<(H * 2 * L + 255) / 256, 256, 0, stream>>>(W_enc_mu, W_enc_lv, Wt_z, H, L, L);
  pack_wt<<<(L * H + 255) / 256, 256, 0, stream>>>(W_dec_h, Wt_dh, L, H);
  pack_wt2<<<(H * 2 * D + 255) / 256, 256, 0, stream>>>(W_dec_mu, W_dec_lv, Wt_dx, H, D, D);
  catf<<<(H + 255) / 256, 256, 0, stream>>>(b_enc_h, b_enc_h, bh, H, 0);
  catf<<<(2 * L + 255) / 256, 256, 0, stream>>>(b_enc_mu, b_enc_lv, bz, L, L);
  catf<<<(H + 255) / 256, 256, 0, stream>>>(b_dec_h, b_dec_h, bdh, H, 0);
  catf<<<(2 * D + 255) / 256, 256, 0, stream>>>(b_dec_mu, b_dec_lv, bdx, D, D);

  // ---- encoder: h = tanh(x @ W_enc_h + b), h stored fp8*64, K-permuted ----
  gemm256<0><<<dim3(H / 256, B / 256), 512, 0, stream>>>(
      xb, Wt_eh, bh, hbuf, INV_4096, 64.f, B, H, D);
  // ---- fused: mu|lv = h @ Wt_z + b ; z = mu + exp(.5 lv) eps (fp8*16) ; KL ----
  gemm_z<<<dim3(1, B / 128), 256, 0, stream>>>(hbuf, Wt_z, bz, eps, zbuf, acc, B, H);
  // ---- decoder hidden: hd = tanh(z @ W_dec_h + b), fp8*64 (K=64: 128^2 kernel) ----
  gemm_bt0<<<dim3(H / 128, B / 128), 256, 0, stream>>>(
      zbuf, Wt_dh, bdh, hbuf, INV_4096, 64.f, B, H, L);
  // ---- logits | lv_x = hd @ [W_dec_mu|W_dec_lv] + b -> fp8*16 (natural cols) ----
  gemm256<2><<<dim3(1024 / 256, B / 256), 512, 0, stream>>>(
      hbuf, Wt_dx, bdx, loglv, INV_16384, 16.f, B, 1024, H);
  // ---- softmax + log-likelihood ----
  lik_kernel<<<B / 32, 256, 0, stream>>>(loglv, x, acc);
  // ---- finalize mean ----
  fin_kernel<<<1, 1, 0, stream>>>(acc, (float*)d_out);
}